// Round 1
// baseline (521.670 us; speedup 1.0000x reference)
//
#include <hip/hip_runtime.h>
#include <hip/hip_bf16.h>

typedef __bf16 bf16;
typedef __attribute__((ext_vector_type(8))) __bf16 bf16x8;
typedef __attribute__((ext_vector_type(4))) __bf16 bf16x4;
typedef __attribute__((ext_vector_type(4))) float f32x4;

typedef const __attribute__((address_space(1))) void* gptr_t;
typedef __attribute__((address_space(3))) void* sptr_t;

__device__ __forceinline__ void gload16(const void* g, void* l) {
  __builtin_amdgcn_global_load_lds((gptr_t)g, (sptr_t)l, 16, 0, 0);
}

#define MFMA_BF16(a, b, c) __builtin_amdgcn_mfma_f32_16x16x32_bf16((a), (b), (c), 0, 0, 0)

namespace {
constexpr int kB = 2, kS = 2048, kE = 2048, kN = 16, kH = 128;
constexpr int kBS = kB * kS;   // 4096
constexpr int kNH = kN * kH;   // 2048
constexpr float kScale = 0.08838834764831845f;  // 1/sqrt(128)
constexpr float kLog2e = 1.4426950408889634f;
}

// ---------------- f32 -> bf16 convert (vectorized) ----------------
__global__ void k_cvt(const float* __restrict__ in, bf16* __restrict__ out) {
  int i = blockIdx.x * 256 + threadIdx.x;
  float4 v = reinterpret_cast<const float4*>(in)[i];
  bf16x4 o = { (bf16)v.x, (bf16)v.y, (bf16)v.z, (bf16)v.w };
  reinterpret_cast<bf16x4*>(out)[i] = o;
}

// ------------- transpose-convert: in[2048][2048] f32 -> out[c][r] bf16 -------------
__global__ void k_tconv(const float* __restrict__ in, bf16* __restrict__ out) {
  __shared__ bf16 tile[64][66];
  int bx = blockIdx.x & 31, by = blockIdx.x >> 5;
  int r0 = by * 64, c0 = bx * 64;
  int t = threadIdx.x;
  int c = t & 63, rb = t >> 6;
#pragma unroll
  for (int j = 0; j < 16; ++j) {
    int r = rb + j * 4;
    tile[r][c] = (bf16)in[(size_t)(r0 + r) * 2048 + c0 + c];
  }
  __syncthreads();
  int rr = t & 63;
#pragma unroll
  for (int j = 0; j < 16; ++j) {
    int cc = rb + j * 4;
    out[(size_t)(c0 + cc) * 2048 + r0 + rr] = tile[rr][cc];
  }
}

// ------------- V transpose: V[bn][S][H] -> Vt[bn][H][S] (bf16) -------------
__global__ void k_vtrans(const bf16* __restrict__ V, bf16* __restrict__ Vt) {
  __shared__ bf16 tile[64][66];
  int bid = blockIdx.x;
  int bn = bid >> 6;
  int s0 = ((bid >> 1) & 31) * 64;
  int h0 = (bid & 1) * 64;
  size_t base = (size_t)bn * kS * kH;
  int t = threadIdx.x, c = t & 63, rb = t >> 6;
#pragma unroll
  for (int j = 0; j < 16; ++j) {
    int r = rb + j * 4;
    tile[r][c] = V[base + (size_t)(s0 + r) * kH + h0 + c];
  }
  __syncthreads();
#pragma unroll
  for (int j = 0; j < 16; ++j) {
    int hh = rb + j * 4;
    Vt[base + (size_t)(h0 + hh) * kS + s0 + (t & 63)] = tile[t & 63][hh];
  }
}

// ------------- RoPE in-place on Q and K, layout [B,N,S,H] -------------
__global__ void k_rope(bf16* __restrict__ Qd, bf16* __restrict__ Kd) {
  int tid = blockIdx.x * 256 + threadIdx.x;   // B*N*S*64 total
  int i = tid & 63;
  int s = (tid >> 6) & (kS - 1);
  int bn = tid >> 17;
  size_t base = ((size_t)bn * kS + s) * kH;
  // inv_timescale = 10000^(-i/64) = exp2(-i * log2(10000)/64)
  float inv = exp2f(-(float)i * 0.20762050593046457f);
  float ang = (float)s * inv;
  float sn, cs;
  sincosf(ang, &sn, &cs);
  float q1 = (float)Qd[base + i], q2 = (float)Qd[base + i + 64];
  Qd[base + i]      = (bf16)(q1 * cs - q2 * sn);
  Qd[base + i + 64] = (bf16)(q2 * cs + q1 * sn);
  float k1 = (float)Kd[base + i], k2 = (float)Kd[base + i + 64];
  Kd[base + i]      = (bf16)(k1 * cs - k2 * sn);
  Kd[base + i + 64] = (bf16)(k2 * cs + k1 * sn);
}

// ------------- GEMM: C[M=4096][N=2048] = A[4096][2048] * Bt[2048][2048]^T -------------
// MODE 0: write bf16 to [B,N,S,H] (QKV). MODE 1: write f32 to [M][2048] (final out).
template <int MODE>
__global__ __launch_bounds__(256, 2) void k_gemm(const bf16* __restrict__ A,
                                                 const bf16* __restrict__ Bt,
                                                 void* __restrict__ Cout) {
  constexpr int Kk = 2048;
  __shared__ __align__(16) bf16 As[128][32];
  __shared__ __align__(16) bf16 Bs[128][32];
  int bid = blockIdx.x;                 // 512 blocks
  int swz = (bid & 7) * 64 + (bid >> 3);  // XCD-aware bijective swizzle
  int mt = swz >> 4, nt = swz & 15;
  int m0 = mt * 128, n0 = nt * 128;
  int t = threadIdx.x, wid = t >> 6, lane = t & 63;
  int l16 = lane & 15, lq = lane >> 4;
  int wr = wid >> 1, wc = wid & 1;
  f32x4 acc[4][4] = {};

  for (int kt = 0; kt < Kk / 32; ++kt) {
    int k0 = kt * 32;
#pragma unroll
    for (int i = 0; i < 2; ++i) {
      int idx = i * 256 + t;
      const bf16* ga = A + (size_t)(m0 + (idx >> 2)) * Kk + k0 + (idx & 3) * 8;
      gload16(ga, (char*)(&As[0][0]) + i * 4096 + wid * 1024);
      const bf16* gb = Bt + (size_t)(n0 + (idx >> 2)) * Kk + k0 + (idx & 3) * 8;
      gload16(gb, (char*)(&Bs[0][0]) + i * 4096 + wid * 1024);
    }
    __syncthreads();
    bf16x8 af[4], bfr[4];
#pragma unroll
    for (int mi = 0; mi < 4; ++mi)
      af[mi] = *(const bf16x8*)&As[wr * 64 + mi * 16 + l16][lq * 8];
#pragma unroll
    for (int ni = 0; ni < 4; ++ni)
      bfr[ni] = *(const bf16x8*)&Bs[wc * 64 + ni * 16 + l16][lq * 8];
#pragma unroll
    for (int mi = 0; mi < 4; ++mi)
#pragma unroll
      for (int ni = 0; ni < 4; ++ni)
        acc[mi][ni] = MFMA_BF16(af[mi], bfr[ni], acc[mi][ni]);
    __syncthreads();
  }

#pragma unroll
  for (int mi = 0; mi < 4; ++mi) {
    int mrow_base = m0 + wr * 64 + mi * 16 + lq * 4;
#pragma unroll
    for (int ni = 0; ni < 4; ++ni) {
      int col = n0 + wc * 64 + ni * 16 + l16;
#pragma unroll
      for (int r = 0; r < 4; ++r) {
        int mrow = mrow_base + r;
        float v = acc[mi][ni][r];
        if (MODE == 0) {
          int b = mrow >> 11, s = mrow & 2047, n = col >> 7, h = col & 127;
          ((bf16*)Cout)[(((size_t)(b * kN + n) * kS + s)) * kH + h] = (bf16)v;
        } else {
          ((float*)Cout)[(size_t)mrow * 2048 + col] = v;
        }
      }
    }
  }
}

// ------------- Flash attention (causal): Q,K [B,N,S,H], Vt [B,N,H,S] -> AO [B,S,N,H] -------------
__global__ __launch_bounds__(256, 2) void k_attn(const bf16* __restrict__ Q,
                                                 const bf16* __restrict__ Kg,
                                                 const bf16* __restrict__ Vt,
                                                 bf16* __restrict__ AO) {
  __shared__ __align__(16) bf16 Ks[64 * 128];   // [s'][h], chunk-swizzled
  __shared__ __align__(16) bf16 Vs[128 * 64];   // [h][s'], chunk-swizzled
  __shared__ __align__(16) bf16 Ps[4][32][72];  // per-wave P, padded
  int bid = blockIdx.x;
  int bn = bid >> 4;
  int qt = bid & 15;
  int q0 = qt * 128;
  int t = threadIdx.x, wid = t >> 6, lane = t & 63;
  int l16 = lane & 15, lq = lane >> 4;
  size_t bnSH = (size_t)bn * kS * kH;

  // Q fragments in registers: wave handles rows [q0+wid*32, +32)
  bf16x8 qf[2][4];
#pragma unroll
  for (int mi = 0; mi < 2; ++mi)
#pragma unroll
    for (int ks = 0; ks < 4; ++ks) {
      int row = q0 + wid * 32 + mi * 16 + l16;
      qf[mi][ks] = *(const bf16x8*)(Q + bnSH + (size_t)row * kH + ks * 32 + lq * 8);
    }

  f32x4 oacc[2][8] = {};
  float mrun[2][4], lrun[2][4];
#pragma unroll
  for (int mi = 0; mi < 2; ++mi)
#pragma unroll
    for (int r = 0; r < 4; ++r) { mrun[mi][r] = -1e30f; lrun[mi][r] = 0.f; }

  int ntiles = (q0 + 128) >> 6;  // causal: kv tiles 0..ntiles-1
  for (int kt = 0; kt < ntiles; ++kt) {
    int kv0 = kt * 64;
    // stage K tile [64][128] and Vt tile [128][64] with source-side chunk swizzle
#pragma unroll
    for (int i = 0; i < 4; ++i) {
      int idx = i * 256 + t;
      {
        int row = idx >> 4, ch = idx & 15;
        int gch = ch ^ (row & 7);
        gload16(Kg + bnSH + (size_t)(kv0 + row) * kH + gch * 8,
                (char*)Ks + i * 4096 + wid * 1024);
      }
      {
        int row = idx >> 3, ch = idx & 7;
        int gch = ch ^ (row & 7);
        gload16(Vt + bnSH + (size_t)row * kS + kv0 + gch * 8,
                (char*)Vs + i * 4096 + wid * 1024);
      }
    }
    __syncthreads();

    // ---- QK^T ----
    f32x4 sacc[2][4] = {};
#pragma unroll
    for (int ks = 0; ks < 4; ++ks) {
#pragma unroll
      for (int ni = 0; ni < 4; ++ni) {
        int sp = ni * 16 + l16;
        int hb = (ks * 32 + lq * 8) * 2;
        bf16x8 kb = *(const bf16x8*)((const char*)Ks + sp * 256 + (hb ^ ((sp & 7) << 4)));
        sacc[0][ni] = MFMA_BF16(qf[0][ks], kb, sacc[0][ni]);
        sacc[1][ni] = MFMA_BF16(qf[1][ks], kb, sacc[1][ni]);
      }
    }

    // ---- scale + causal mask ----
    bool need_mask = (kv0 + 63) > q0;
#pragma unroll
    for (int mi = 0; mi < 2; ++mi)
#pragma unroll
      for (int ni = 0; ni < 4; ++ni) {
        f32x4 v = sacc[mi][ni] * kScale;
        if (need_mask) {
#pragma unroll
          for (int r = 0; r < 4; ++r) {
            int qrow = q0 + wid * 32 + mi * 16 + lq * 4 + r;
            int col = kv0 + ni * 16 + l16;
            if (col > qrow) v[r] = -1e30f;
          }
        }
        sacc[mi][ni] = v;
      }

    // ---- online softmax (rows spread over 16-lane groups) ----
#pragma unroll
    for (int mi = 0; mi < 2; ++mi)
#pragma unroll
      for (int r = 0; r < 4; ++r) {
        float pm = fmaxf(fmaxf(sacc[mi][0][r], sacc[mi][1][r]),
                         fmaxf(sacc[mi][2][r], sacc[mi][3][r]));
        pm = fmaxf(pm, __shfl_xor(pm, 1));
        pm = fmaxf(pm, __shfl_xor(pm, 2));
        pm = fmaxf(pm, __shfl_xor(pm, 4));
        pm = fmaxf(pm, __shfl_xor(pm, 8));
        float mold = mrun[mi][r];
        float mnew = fmaxf(mold, pm);
        float alpha = exp2f((mold - mnew) * kLog2e);
        mrun[mi][r] = mnew;
        float rs = 0.f;
#pragma unroll
        for (int ni = 0; ni < 4; ++ni) {
          float p = exp2f((sacc[mi][ni][r] - mnew) * kLog2e);
          sacc[mi][ni][r] = p;
          rs += p;
        }
        rs += __shfl_xor(rs, 1);
        rs += __shfl_xor(rs, 2);
        rs += __shfl_xor(rs, 4);
        rs += __shfl_xor(rs, 8);
        lrun[mi][r] = lrun[mi][r] * alpha + rs;
#pragma unroll
        for (int nj = 0; nj < 8; ++nj) oacc[mi][nj][r] *= alpha;
      }

    // ---- write P (bf16) to per-wave LDS ----
#pragma unroll
    for (int mi = 0; mi < 2; ++mi)
#pragma unroll
      for (int ni = 0; ni < 4; ++ni)
#pragma unroll
        for (int r = 0; r < 4; ++r)
          Ps[wid][mi * 16 + lq * 4 + r][ni * 16 + l16] = (bf16)sacc[mi][ni][r];

    // ---- PV ----
#pragma unroll
    for (int ks = 0; ks < 2; ++ks) {
      bf16x8 pa0 = *(const bf16x8*)&Ps[wid][l16][ks * 32 + lq * 8];
      bf16x8 pa1 = *(const bf16x8*)&Ps[wid][16 + l16][ks * 32 + lq * 8];
#pragma unroll
      for (int nj = 0; nj < 8; ++nj) {
        int h = nj * 16 + l16;
        int sb = (ks * 64 + lq * 16) ^ ((h & 7) << 4);
        bf16x8 vb = *(const bf16x8*)((const char*)Vs + h * 128 + sb);
        oacc[0][nj] = MFMA_BF16(pa0, vb, oacc[0][nj]);
        oacc[1][nj] = MFMA_BF16(pa1, vb, oacc[1][nj]);
      }
    }
    __syncthreads();
  }

  // ---- epilogue: normalize, write AO [B,S,N,H] ----
  int b = bn >> 4, n = bn & 15;
#pragma unroll
  for (int mi = 0; mi < 2; ++mi)
#pragma unroll
    for (int r = 0; r < 4; ++r) {
      float inv = 1.0f / lrun[mi][r];
      int qrow = q0 + wid * 32 + mi * 16 + lq * 4 + r;
#pragma unroll
      for (int nj = 0; nj < 8; ++nj) {
        float v = oacc[mi][nj][r] * inv;
        AO[(((size_t)b * kS + qrow) * kN + n) * kH + nj * 16 + l16] = (bf16)v;
      }
    }
}

extern "C" void kernel_launch(void* const* d_in, const int* in_sizes, int n_in,
                              void* d_out, int out_size, void* d_ws, size_t ws_size,
                              hipStream_t stream) {
  (void)in_sizes; (void)n_in; (void)out_size; (void)ws_size;
  const float* x_q  = (const float*)d_in[0];
  const float* x_kv = (const float*)d_in[1];
  const float* WQ   = (const float*)d_in[2];
  const float* WK   = (const float*)d_in[3];
  const float* WV   = (const float*)d_in[4];
  const float* WO   = (const float*)d_in[5];
  float* out = (float*)d_out;
  char* w = (char*)d_ws;
  const size_t MB = 1ull << 20;
  bf16* xq  = (bf16*)(w + 0 * MB);    // 16MB, reused as AO after Q-GEMM
  bf16* xkv = (bf16*)(w + 16 * MB);   // 16MB, reused as Vt after V-GEMM
  bf16* WqT = (bf16*)(w + 32 * MB);   // 8MB
  bf16* WkT = (bf16*)(w + 40 * MB);   // 8MB
  bf16* WvT = (bf16*)(w + 48 * MB);   // 8MB
  bf16* WoT = (bf16*)(w + 56 * MB);   // 8MB
  bf16* Qb  = (bf16*)(w + 64 * MB);   // 16MB [B,N,S,H]
  bf16* Kb  = (bf16*)(w + 80 * MB);   // 16MB [B,N,S,H]
  bf16* Vb  = (bf16*)(w + 96 * MB);   // 16MB [B,N,S,H]
  bf16* AO  = xq;                     // [B,S,N,H]
  bf16* Vtb = xkv;                    // [B,N,H,S]

  k_cvt<<<8192, 256, 0, stream>>>(x_q, xq);
  k_cvt<<<8192, 256, 0, stream>>>(x_kv, xkv);
  k_tconv<<<1024, 256, 0, stream>>>(WQ, WqT);
  k_tconv<<<1024, 256, 0, stream>>>(WK, WkT);
  k_tconv<<<1024, 256, 0, stream>>>(WV, WvT);
  k_tconv<<<1024, 256, 0, stream>>>(WO, WoT);
  k_gemm<0><<<512, 256, 0, stream>>>(xq,  WqT, Qb);
  k_gemm<0><<<512, 256, 0, stream>>>(xkv, WkT, Kb);
  k_gemm<0><<<512, 256, 0, stream>>>(xkv, WvT, Vb);
  k_rope<<<16384, 256, 0, stream>>>(Qb, Kb);
  k_vtrans<<<2048, 256, 0, stream>>>(Vb, Vtb);
  k_attn<<<512, 256, 0, stream>>>(Qb, Kb, Vtb, AO);
  k_gemm<1><<<512, 256, 0, stream>>>(AO, WoT, out);
}

// Round 2
// 471.497 us; speedup vs baseline: 1.1064x; 1.1064x over previous
//
#include <hip/hip_runtime.h>
#include <hip/hip_bf16.h>

typedef __bf16 bf16;
typedef __attribute__((ext_vector_type(8))) __bf16 bf16x8;
typedef __attribute__((ext_vector_type(4))) __bf16 bf16x4;
typedef __attribute__((ext_vector_type(4))) float f32x4;

typedef const __attribute__((address_space(1))) void* gptr_t;
typedef __attribute__((address_space(3))) void* sptr_t;

__device__ __forceinline__ void gload16(const void* g, void* l) {
  __builtin_amdgcn_global_load_lds((gptr_t)g, (sptr_t)l, 16, 0, 0);
}

#define MFMA_BF16(a, b, c) __builtin_amdgcn_mfma_f32_16x16x32_bf16((a), (b), (c), 0, 0, 0)

namespace {
constexpr int kB = 2, kS = 2048, kE = 2048, kN = 16, kH = 128;
constexpr int kBS = kB * kS;   // 4096
constexpr int kNH = kN * kH;   // 2048
constexpr float kScale = 0.08838834764831845f;  // 1/sqrt(128)
constexpr float kLog2e = 1.4426950408889634f;
}

// ---------------- f32 -> bf16 convert (vectorized) ----------------
__global__ void k_cvt(const float* __restrict__ in, bf16* __restrict__ out) {
  int i = blockIdx.x * 256 + threadIdx.x;
  float4 v = reinterpret_cast<const float4*>(in)[i];
  bf16x4 o = { (bf16)v.x, (bf16)v.y, (bf16)v.z, (bf16)v.w };
  reinterpret_cast<bf16x4*>(out)[i] = o;
}

// ------------- transpose-convert: in[2048][2048] f32 -> out[c][r] bf16 -------------
__global__ void k_tconv(const float* __restrict__ in, bf16* __restrict__ out) {
  __shared__ bf16 tile[64][66];
  int bx = blockIdx.x & 31, by = blockIdx.x >> 5;
  int r0 = by * 64, c0 = bx * 64;
  int t = threadIdx.x;
  int c = t & 63, rb = t >> 6;
#pragma unroll
  for (int j = 0; j < 16; ++j) {
    int r = rb + j * 4;
    tile[r][c] = (bf16)in[(size_t)(r0 + r) * 2048 + c0 + c];
  }
  __syncthreads();
  int rr = t & 63;
#pragma unroll
  for (int j = 0; j < 16; ++j) {
    int cc = rb + j * 4;
    out[(size_t)(c0 + cc) * 2048 + r0 + rr] = tile[rr][cc];
  }
}

// ------------- V transpose: V[bn][S][H] -> Vt[bn][H][S] (bf16) -------------
__global__ void k_vtrans(const bf16* __restrict__ V, bf16* __restrict__ Vt) {
  __shared__ bf16 tile[64][66];
  int bid = blockIdx.x;
  int bn = bid >> 6;
  int s0 = ((bid >> 1) & 31) * 64;
  int h0 = (bid & 1) * 64;
  size_t base = (size_t)bn * kS * kH;
  int t = threadIdx.x, c = t & 63, rb = t >> 6;
#pragma unroll
  for (int j = 0; j < 16; ++j) {
    int r = rb + j * 4;
    tile[r][c] = V[base + (size_t)(s0 + r) * kH + h0 + c];
  }
  __syncthreads();
#pragma unroll
  for (int j = 0; j < 16; ++j) {
    int hh = rb + j * 4;
    Vt[base + (size_t)(h0 + hh) * kS + s0 + (t & 63)] = tile[t & 63][hh];
  }
}

// ------------- RoPE in-place on Q and K, layout [B,N,S,H] -------------
__global__ void k_rope(bf16* __restrict__ Qd, bf16* __restrict__ Kd) {
  int tid = blockIdx.x * 256 + threadIdx.x;   // B*N*S*64 total
  int i = tid & 63;
  int s = (tid >> 6) & (kS - 1);
  int bn = tid >> 17;
  size_t base = ((size_t)bn * kS + s) * kH;
  // inv_timescale = 10000^(-i/64) = exp2(-i * log2(10000)/64)
  float inv = exp2f(-(float)i * 0.20762050593046457f);
  float ang = (float)s * inv;
  float sn, cs;
  sincosf(ang, &sn, &cs);
  float q1 = (float)Qd[base + i], q2 = (float)Qd[base + i + 64];
  Qd[base + i]      = (bf16)(q1 * cs - q2 * sn);
  Qd[base + i + 64] = (bf16)(q2 * cs + q1 * sn);
  float k1 = (float)Kd[base + i], k2 = (float)Kd[base + i + 64];
  Kd[base + i]      = (bf16)(k1 * cs - k2 * sn);
  Kd[base + i + 64] = (bf16)(k2 * cs + k1 * sn);
}

// ------------- GEMM: C[M=4096][N=2048] = A[4096][2048] * Bt[2048][2048]^T -------------
// MODE 0: write bf16 to [B,N,S,H] (QKV). MODE 1: write f32 to [M][2048] (final out).
template <int MODE>
__global__ __launch_bounds__(256, 2) void k_gemm(const bf16* __restrict__ A,
                                                 const bf16* __restrict__ Bt,
                                                 void* __restrict__ Cout) {
  constexpr int Kk = 2048;
  __shared__ __align__(16) bf16 As[128][32];
  __shared__ __align__(16) bf16 Bs[128][32];
  int bid = blockIdx.x;                 // 512 blocks
  int swz = (bid & 7) * 64 + (bid >> 3);  // XCD-aware bijective swizzle
  int mt = swz >> 4, nt = swz & 15;
  int m0 = mt * 128, n0 = nt * 128;
  int t = threadIdx.x, wid = t >> 6, lane = t & 63;
  int l16 = lane & 15, lq = lane >> 4;
  int wr = wid >> 1, wc = wid & 1;
  f32x4 acc[4][4] = {};

  for (int kt = 0; kt < Kk / 32; ++kt) {
    int k0 = kt * 32;
#pragma unroll
    for (int i = 0; i < 2; ++i) {
      int idx = i * 256 + t;
      const bf16* ga = A + (size_t)(m0 + (idx >> 2)) * Kk + k0 + (idx & 3) * 8;
      gload16(ga, (char*)(&As[0][0]) + i * 4096 + wid * 1024);
      const bf16* gb = Bt + (size_t)(n0 + (idx >> 2)) * Kk + k0 + (idx & 3) * 8;
      gload16(gb, (char*)(&Bs[0][0]) + i * 4096 + wid * 1024);
    }
    __syncthreads();
    bf16x8 af[4], bfr[4];
#pragma unroll
    for (int mi = 0; mi < 4; ++mi)
      af[mi] = *(const bf16x8*)&As[wr * 64 + mi * 16 + l16][lq * 8];
#pragma unroll
    for (int ni = 0; ni < 4; ++ni)
      bfr[ni] = *(const bf16x8*)&Bs[wc * 64 + ni * 16 + l16][lq * 8];
#pragma unroll
    for (int mi = 0; mi < 4; ++mi)
#pragma unroll
      for (int ni = 0; ni < 4; ++ni)
        acc[mi][ni] = MFMA_BF16(af[mi], bfr[ni], acc[mi][ni]);
    __syncthreads();
  }

#pragma unroll
  for (int mi = 0; mi < 4; ++mi) {
    int mrow_base = m0 + wr * 64 + mi * 16 + lq * 4;
#pragma unroll
    for (int ni = 0; ni < 4; ++ni) {
      int col = n0 + wc * 64 + ni * 16 + l16;
#pragma unroll
      for (int r = 0; r < 4; ++r) {
        int mrow = mrow_base + r;
        float v = acc[mi][ni][r];
        if (MODE == 0) {
          int b = mrow >> 11, s = mrow & 2047, n = col >> 7, h = col & 127;
          ((bf16*)Cout)[(((size_t)(b * kN + n) * kS + s)) * kH + h] = (bf16)v;
        } else {
          ((float*)Cout)[(size_t)mrow * 2048 + col] = v;
        }
      }
    }
  }
}

// ------------- Flash attention (causal): Q,K [B,N,S,H], Vt [B,N,H,S] -> AO [B,S,N,H] -------------
// 512 threads / 8 waves; wave owns 16 q-rows. Whole grid (512 blocks) is co-resident
// at 2 blocks/CU; bid remap pairs qt with 15-qt on the same CU for uniform work.
__global__ __launch_bounds__(512, 4) void k_attn(const bf16* __restrict__ Q,
                                                 const bf16* __restrict__ Kg,
                                                 const bf16* __restrict__ Vt,
                                                 bf16* __restrict__ AO) {
  __shared__ __align__(16) bf16 Ks[64 * 128];   // [s'][h], chunk-swizzled
  __shared__ __align__(16) bf16 Vs[128 * 64];   // [h][s'], chunk-swizzled
  __shared__ __align__(16) bf16 Ps[8][16][72];  // per-wave P, padded
  int bid = blockIdx.x;
  // complementary pairing: co-resident blocks (bid, bid+256) get qt and 15-qt
  int half = bid >> 8;                       // 0 or 1
  int bn = (half << 4) | ((bid >> 4) & 15);  // 0..31
  int qt = (bid & 15) ^ (half ? 15 : 0);     // half=1 -> 15-qt
  int q0 = qt * 128;
  int t = threadIdx.x, wid = t >> 6, lane = t & 63;
  int l16 = lane & 15, lq = lane >> 4;
  size_t bnSH = (size_t)bn * kS * kH;

  // Q fragments in registers: wave handles rows [q0+wid*16, +16)
  int qrow_a = q0 + wid * 16 + l16;   // A-fragment row for this lane
  bf16x8 qf[4];
#pragma unroll
  for (int ks = 0; ks < 4; ++ks)
    qf[ks] = *(const bf16x8*)(Q + bnSH + (size_t)qrow_a * kH + ks * 32 + lq * 8);

  f32x4 oacc[8] = {};
  float mrun[4], lrun[4];
#pragma unroll
  for (int r = 0; r < 4; ++r) { mrun[r] = -1e30f; lrun[r] = 0.f; }

  int ntiles = (q0 + 128) >> 6;  // causal: kv tiles 0..ntiles-1
  for (int kt = 0; kt < ntiles; ++kt) {
    int kv0 = kt * 64;
    // stage K tile [64][128] and Vt tile [128][64] with source-side chunk swizzle
#pragma unroll
    for (int i = 0; i < 2; ++i) {
      int idx = i * 512 + t;   // 0..1023
      {
        int row = idx >> 4, ch = idx & 15;
        int gch = ch ^ (row & 7);
        gload16(Kg + bnSH + (size_t)(kv0 + row) * kH + gch * 8,
                (char*)Ks + i * 8192 + wid * 1024);
      }
      {
        int row = idx >> 3, ch = idx & 7;
        int gch = ch ^ (row & 7);
        gload16(Vt + bnSH + (size_t)row * kS + kv0 + gch * 8,
                (char*)Vs + i * 8192 + wid * 1024);
      }
    }
    __syncthreads();

    // ---- QK^T ----  (C: col=l16 -> kv, row=lq*4+r -> q-row within wave's 16)
    f32x4 sacc[4] = {};
#pragma unroll
    for (int ks = 0; ks < 4; ++ks) {
#pragma unroll
      for (int ni = 0; ni < 4; ++ni) {
        int sp = ni * 16 + l16;
        int hb = (ks * 32 + lq * 8) * 2;
        bf16x8 kb = *(const bf16x8*)((const char*)Ks + sp * 256 + (hb ^ ((sp & 7) << 4)));
        sacc[ni] = MFMA_BF16(qf[ks], kb, sacc[ni]);
      }
    }

    // ---- scale + causal mask ----
    bool need_mask = (kv0 + 63) > (q0 + wid * 16);
#pragma unroll
    for (int ni = 0; ni < 4; ++ni) {
      f32x4 v = sacc[ni] * kScale;
      if (need_mask) {
#pragma unroll
        for (int r = 0; r < 4; ++r) {
          int qrow = q0 + wid * 16 + lq * 4 + r;
          int col = kv0 + ni * 16 + l16;
          if (col > qrow) v[r] = -1e30f;
        }
      }
      sacc[ni] = v;
    }

    // ---- online softmax (row r lives in lanes sharing lq; reduce over l16) ----
#pragma unroll
    for (int r = 0; r < 4; ++r) {
      float pm = fmaxf(fmaxf(sacc[0][r], sacc[1][r]),
                       fmaxf(sacc[2][r], sacc[3][r]));
      pm = fmaxf(pm, __shfl_xor(pm, 1));
      pm = fmaxf(pm, __shfl_xor(pm, 2));
      pm = fmaxf(pm, __shfl_xor(pm, 4));
      pm = fmaxf(pm, __shfl_xor(pm, 8));
      float mold = mrun[r];
      float mnew = fmaxf(mold, pm);
      float alpha = exp2f((mold - mnew) * kLog2e);
      mrun[r] = mnew;
      float rs = 0.f;
#pragma unroll
      for (int ni = 0; ni < 4; ++ni) {
        float p = exp2f((sacc[ni][r] - mnew) * kLog2e);
        sacc[ni][r] = p;
        rs += p;
      }
      rs += __shfl_xor(rs, 1);
      rs += __shfl_xor(rs, 2);
      rs += __shfl_xor(rs, 4);
      rs += __shfl_xor(rs, 8);
      lrun[r] = lrun[r] * alpha + rs;
#pragma unroll
      for (int nj = 0; nj < 8; ++nj) oacc[nj][r] *= alpha;
    }

    // ---- write P (bf16) to per-wave LDS ----
#pragma unroll
    for (int ni = 0; ni < 4; ++ni)
#pragma unroll
      for (int r = 0; r < 4; ++r)
        Ps[wid][lq * 4 + r][ni * 16 + l16] = (bf16)sacc[ni][r];

    // ---- PV ----
#pragma unroll
    for (int ks = 0; ks < 2; ++ks) {
      bf16x8 pa = *(const bf16x8*)&Ps[wid][l16][ks * 32 + lq * 8];
#pragma unroll
      for (int nj = 0; nj < 8; ++nj) {
        int h = nj * 16 + l16;
        int sb = (ks * 64 + lq * 16) ^ ((h & 7) << 4);
        bf16x8 vb = *(const bf16x8*)((const char*)Vs + h * 128 + sb);
        oacc[nj] = MFMA_BF16(pa, vb, oacc[nj]);
      }
    }
    __syncthreads();
  }

  // ---- epilogue: normalize, write AO [B,S,N,H] ----
  int b = bn >> 4, n = bn & 15;
#pragma unroll
  for (int r = 0; r < 4; ++r) {
    float inv = 1.0f / lrun[r];
    int qrow = q0 + wid * 16 + lq * 4 + r;
#pragma unroll
    for (int nj = 0; nj < 8; ++nj) {
      float v = oacc[nj][r] * inv;
      AO[(((size_t)b * kS + qrow) * kN + n) * kH + nj * 16 + l16] = (bf16)v;
    }
  }
}

extern "C" void kernel_launch(void* const* d_in, const int* in_sizes, int n_in,
                              void* d_out, int out_size, void* d_ws, size_t ws_size,
                              hipStream_t stream) {
  (void)in_sizes; (void)n_in; (void)out_size; (void)ws_size;
  const float* x_q  = (const float*)d_in[0];
  const float* x_kv = (const float*)d_in[1];
  const float* WQ   = (const float*)d_in[2];
  const float* WK   = (const float*)d_in[3];
  const float* WV   = (const float*)d_in[4];
  const float* WO   = (const float*)d_in[5];
  float* out = (float*)d_out;
  char* w = (char*)d_ws;
  const size_t MB = 1ull << 20;
  bf16* xq  = (bf16*)(w + 0 * MB);    // 16MB, reused as AO after Q-GEMM
  bf16* xkv = (bf16*)(w + 16 * MB);   // 16MB, reused as Vt after V-GEMM
  bf16* WqT = (bf16*)(w + 32 * MB);   // 8MB
  bf16* WkT = (bf16*)(w + 40 * MB);   // 8MB
  bf16* WvT = (bf16*)(w + 48 * MB);   // 8MB
  bf16* WoT = (bf16*)(w + 56 * MB);   // 8MB
  bf16* Qb  = (bf16*)(w + 64 * MB);   // 16MB [B,N,S,H]
  bf16* Kb  = (bf16*)(w + 80 * MB);   // 16MB [B,N,S,H]
  bf16* Vb  = (bf16*)(w + 96 * MB);   // 16MB [B,N,S,H]
  bf16* AO  = xq;                     // [B,S,N,H]
  bf16* Vtb = xkv;                    // [B,N,H,S]

  k_cvt<<<8192, 256, 0, stream>>>(x_q, xq);
  k_cvt<<<8192, 256, 0, stream>>>(x_kv, xkv);
  k_tconv<<<1024, 256, 0, stream>>>(WQ, WqT);
  k_tconv<<<1024, 256, 0, stream>>>(WK, WkT);
  k_tconv<<<1024, 256, 0, stream>>>(WV, WvT);
  k_tconv<<<1024, 256, 0, stream>>>(WO, WoT);
  k_gemm<0><<<512, 256, 0, stream>>>(xq,  WqT, Qb);
  k_gemm<0><<<512, 256, 0, stream>>>(xkv, WkT, Kb);
  k_gemm<0><<<512, 256, 0, stream>>>(xkv, WvT, Vb);
  k_rope<<<16384, 256, 0, stream>>>(Qb, Kb);
  k_vtrans<<<2048, 256, 0, stream>>>(Vb, Vtb);
  k_attn<<<512, 512, 0, stream>>>(Qb, Kb, Vtb, AO);
  k_gemm<1><<<512, 256, 0, stream>>>(AO, WoT, out);
}